// Round 8
// baseline (69.763 us; speedup 1.0000x reference)
//
#include <hip/hip_runtime.h>

#define MAX_LEN 16384
#define RES_LEN 16372   // (16384 - 4) - 9 + 1
#define NSEG    8       // segments per row
#define SEG     2048    // outputs per segment (last = 2036)

// Fast-path: all window indices compile-time static (O0 = (-D) & 3 is
// regime-uniform). Processes output quads g in [gA, gB], stride 256.
template<int O0>
__device__ void fast_regime(
    int gA, int gB, int tid, unsigned D, unsigned j_lo_al, unsigned p2_i0,
    const float4* __restrict__ resS4, const float* __restrict__ a2S,
    const float* __restrict__ m2S,
    float4* __restrict__ o0p, float4* __restrict__ o1p,
    float4* __restrict__ o2p, float4* __restrict__ o3p)
{
    const float inv9 = 1.0f / 9.0f;
    for (int g = gA + tid; g <= gB; g += 256) {
        const unsigned iq0 = 4u * (unsigned)g;
        const unsigned li0 = iq0 - D - j_lo_al;   // p1(iq0) - j_lo_al; (li0&3)==O0
        const unsigned q   = li0 >> 2;
        float4 W0 = resS4[q], W1 = resS4[q + 1], W2 = resS4[q + 2], W3 = resS4[q + 3];
        float w[16];
        w[0]=W0.x;  w[1]=W0.y;  w[2]=W0.z;  w[3]=W0.w;
        w[4]=W1.x;  w[5]=W1.y;  w[6]=W1.z;  w[7]=W1.w;
        w[8]=W2.x;  w[9]=W2.y;  w[10]=W2.z; w[11]=W2.w;
        w[12]=W3.x; w[13]=W3.y; w[14]=W3.z; w[15]=W3.w;

        // static sliding 9-sums, windows start O0+k (no d-step inside quad)
        float S0 = ((((((((w[O0]+w[O0+1])+w[O0+2])+w[O0+3])+w[O0+4])+w[O0+5])+w[O0+6])+w[O0+7])+w[O0+8]);
        float S1 = S0 - w[O0]     + w[O0+9];
        float S2 = S1 - w[O0+1]   + w[O0+10];
        float S3 = S2 - w[O0+2]   + w[O0+11];

        // static 9-maxes: suffix chain to pivot O0+8, small prefix beyond
        float c8 = w[O0+8];
        float c7 = fmaxf(w[O0+7], c8);
        float c6 = fmaxf(w[O0+6], c7);
        float c5 = fmaxf(w[O0+5], c6);
        float c4 = fmaxf(w[O0+4], c5);
        float c3 = fmaxf(w[O0+3], c4);
        float c2 = fmaxf(w[O0+2], c3);
        float c1 = fmaxf(w[O0+1], c2);
        float c0 = fmaxf(w[O0+0], c1);
        float p10 = fmaxf(w[O0+9], w[O0+10]);
        float mx0 = c0;
        float mx1 = fmaxf(c1, w[O0+9]);
        float mx2 = fmaxf(c2, p10);
        float mx3 = fmaxf(c3, fmaxf(p10, w[O0+11]));

        const float4 R = resS4[(iq0 - j_lo_al) >> 2];

        const unsigned p2_0 = (iq0 * 1819u) / 16372u;
        const unsigned p2_1 = ((iq0 + 1u) * 1819u) / 16372u;
        const unsigned p2_2 = ((iq0 + 2u) * 1819u) / 16372u;
        const unsigned p2_3 = ((iq0 + 3u) * 1819u) / 16372u;
        const float a2l = a2S[p2_0 - p2_i0], a2h = a2S[p2_3 - p2_i0];
        const float m2l = m2S[p2_0 - p2_i0], m2h = m2S[p2_3 - p2_i0];
        const float a2_1 = (p2_1 != p2_0) ? a2h : a2l;
        const float a2_2 = (p2_2 != p2_0) ? a2h : a2l;
        const float m2_1 = (p2_1 != p2_0) ? m2h : m2l;
        const float m2_2 = (p2_2 != p2_0) ? m2h : m2l;

        float4 v0, v1, v2, v3;
        v0.x = S0 * inv9 + R.x; v0.y = S1 * inv9 + R.y; v0.z = S2 * inv9 + R.z; v0.w = S3 * inv9 + R.w;
        v1.x = a2l + R.x;       v1.y = a2_1 + R.y;      v1.z = a2_2 + R.z;      v1.w = a2h + R.w;
        v2.x = mx0 + R.x;       v2.y = mx1 + R.y;       v2.z = mx2 + R.z;       v2.w = mx3 + R.w;
        v3.x = m2l + R.x;       v3.y = m2_1 + R.y;      v3.z = m2_2 + R.z;      v3.w = m2h + R.w;

        o0p[g] = v0; o1p[g] = v1; o2p[g] = v2; o3p[g] = v3;
    }
}

__global__ __launch_bounds__(256, 6)
void derive_kernel(const float* __restrict__ x, float* __restrict__ out) {
    const int bid = blockIdx.x;
    const int b = bid >> 5;
    const int c = (bid >> 3) & 3;
    const int s = bid & 7;

    const float*  __restrict__ xr  = x + (size_t)b * MAX_LEN;
    const float4* __restrict__ xr4 = (const float4*)xr;

    // ---- segment geometry (unsigned-32 safe) ----
    const unsigned i0     = (unsigned)s * SEG;
    const unsigned i_last = (s == NSEG - 1) ? (RES_LEN - 1) : (i0 + SEG - 1);
    const unsigned p1_i0  = (i0 * 16364u) / 16372u;
    const unsigned p2_i0  = (i0 * 1819u)  / 16372u;
    const unsigned p1_lst = (i_last * 16364u) / 16372u;
    const unsigned p2_lst = (i_last * 1819u)  / 16372u;
    const unsigned j_lo   = (p1_i0 < 9u * p2_i0) ? p1_i0 : 9u * p2_i0;
    const unsigned j_lo_al = j_lo & ~3u;
    const unsigned j_hi_a = p1_lst, j_hi_b = 9u * p2_lst;
    const unsigned j_hi   = ((j_hi_a > j_hi_b) ? j_hi_a : j_hi_b) + 8u;
    const int      nqw    = (int)((j_hi - j_lo_al + 1u + 3u) >> 2);
    const int      xqb    = (int)(j_lo_al >> 2);
    const int      np2    = (int)(p2_lst - p2_i0 + 1u);

    __shared__ float4 resS4[524];
    __shared__ float  a2S[232];
    __shared__ float  m2S[232];
    float* resS = (float*)resS4;

    const float inv9 = 1.0f / 9.0f;
    const int tid = threadIdx.x;

    // ---- Phase 1: res window into LDS (telescoped 9-avg of shifted diffs) ----
    for (int g = tid; g < nqw; g += 256) {
        const int gi = xqb + g;
        float4 A  = xr4[gi];
        float4 B4 = xr4[min(gi + 1, 4095)];
        float4 C4 = xr4[min(gi + 2, 4095)];
        float4 D4 = xr4[min(gi + 3, 4095)];
        float xv[16];
        xv[0]=A.x;  xv[1]=A.y;  xv[2]=A.z;  xv[3]=A.w;
        xv[4]=B4.x; xv[5]=B4.y; xv[6]=B4.z; xv[7]=B4.w;
        xv[8]=C4.x; xv[9]=C4.y; xv[10]=C4.z; xv[11]=C4.w;
        xv[12]=D4.x; xv[13]=D4.y; xv[14]=D4.z; xv[15]=D4.w;
        float rr[4];
        if (c == 0) {
            #pragma unroll
            for (int j = 0; j < 4; ++j) rr[j] = (xv[j+12] - xv[j+3]) * inv9;
        } else if (c == 1) {
            #pragma unroll
            for (int j = 0; j < 4; ++j) rr[j] = ((xv[j+12] + xv[j+11]) - (xv[j+3] + xv[j+2])) * inv9;
        } else if (c == 2) {
            #pragma unroll
            for (int j = 0; j < 4; ++j) rr[j] = ((xv[j+9] + xv[j+10] + xv[j+11] + xv[j+12])
                                               - (xv[j] + xv[j+1] + xv[j+2] + xv[j+3])) * inv9;
        } else {
            #pragma unroll
            for (int j = 0; j < 4; ++j) rr[j] = ((xv[j+12] - xv[j+11]) - (xv[j+3] - xv[j+2])) * inv9;
        }
        float4 rv; rv.x = rr[0]; rv.y = rr[1]; rv.z = rr[2]; rv.w = rr[3];
        resS4[g] = rv;
    }
    __syncthreads();

    // ---- Phase 2: local stride-9 pools ----
    for (int t = tid; t < np2; t += 256) {
        const int j0 = (int)(9u * (p2_i0 + (unsigned)t) - j_lo_al);
        float sm = resS[j0], mm = resS[j0];
        #pragma unroll
        for (int k = 1; k < 9; ++k) { float v = resS[j0 + k]; sm += v; mm = fmaxf(mm, v); }
        a2S[t] = sm * inv9; m2S[t] = mm;
    }
    __syncthreads();

    // ---- Phase 3: regime-split with static window offsets ----
    float* outBase = out + ((size_t)b * 16 + c) * RES_LEN;
    float4* o0p = (float4*)(outBase);
    float4* o1p = (float4*)(outBase + 4 * RES_LEN);
    float4* o2p = (float4*)(outBase + 8 * RES_LEN);
    float4* o3p = (float4*)(outBase + 12 * RES_LEN);

    // d(i) = ceil(2i/4093); p1(i) = i - d(i).
    // d(i) = m holds for i <= floor(4093*m/2); first i with d = m+1 is
    // floor(4093*m/2) + 1.  (R7 bug: used m+1/m+2 instead of m/m+1.)
    const unsigned d_i0 = (8u * i0 + 16371u) / 16372u;
    const unsigned bA = ((4093u * d_i0) >> 1) + 1u;          // d -> d_i0+1
    const unsigned bB = ((4093u * (d_i0 + 1u)) >> 1) + 1u;   // d -> d_i0+2
    const int nb = (bA <= i_last ? 1 : 0) + (bB <= i_last ? 1 : 0);

    // General path for boundary-straddling quads (verified R5 math).
    auto general_quad = [&](int gq) {
        const unsigned iq0 = 4u * (unsigned)gq;
        const unsigned p1_0 = (iq0 * 16364u) / 16372u;
        const unsigned p1_1 = ((iq0 + 1u) * 16364u) / 16372u;
        const unsigned p1_2 = ((iq0 + 2u) * 16364u) / 16372u;
        const unsigned p1_3 = ((iq0 + 3u) * 16364u) / 16372u;
        const unsigned p2_0 = (iq0 * 1819u) / 16372u;
        const unsigned p2_1 = ((iq0 + 1u) * 1819u) / 16372u;
        const unsigned p2_2 = ((iq0 + 2u) * 1819u) / 16372u;
        const unsigned p2_3 = ((iq0 + 3u) * 1819u) / 16372u;
        const unsigned li0 = p1_0 - j_lo_al;
        const unsigned q   = li0 >> 2;
        const unsigned o0  = li0 & 3u;
        const unsigned o1  = (p1_1 - j_lo_al) - 4u * q;
        const unsigned o2  = (p1_2 - j_lo_al) - 4u * q;
        const unsigned o3  = (p1_3 - j_lo_al) - 4u * q;
        float4 W0 = resS4[q], W1 = resS4[q + 1], W2 = resS4[q + 2], W3 = resS4[q + 3];
        float w[16];
        w[0]=W0.x;  w[1]=W0.y;  w[2]=W0.z;  w[3]=W0.w;
        w[4]=W1.x;  w[5]=W1.y;  w[6]=W1.z;  w[7]=W1.w;
        w[8]=W2.x;  w[9]=W2.y;  w[10]=W2.z; w[11]=W2.w;
        w[12]=W3.x; w[13]=W3.y; w[14]=W3.z; w[15]=W3.w;
        float s_[7];
        s_[0] = ((((((((w[0] + w[1]) + w[2]) + w[3]) + w[4]) + w[5]) + w[6]) + w[7]) + w[8]);
        #pragma unroll
        for (int e = 1; e < 7; ++e) s_[e] = s_[e - 1] - w[e - 1] + w[e + 8];
        float suf[7];
        suf[6] = fmaxf(fmaxf(w[6], w[7]), w[8]);
        #pragma unroll
        for (int u = 5; u >= 0; --u) suf[u] = fmaxf(w[u], suf[u + 1]);
        float pre[15];
        pre[8] = w[8];
        #pragma unroll
        for (int u = 9; u < 15; ++u) pre[u] = fmaxf(pre[u - 1], w[u]);
        float m_[7];
        #pragma unroll
        for (int o = 0; o < 7; ++o) m_[o] = fmaxf(suf[o], pre[o + 8]);
        float sum0 = s_[0], sum1 = s_[0], sum2 = s_[0], sum3 = s_[0];
        float mx0  = m_[0], mx1  = m_[0], mx2  = m_[0], mx3  = m_[0];
        #pragma unroll
        for (int e = 1; e <= 3; ++e) { bool t_ = (o0 >= (unsigned)e); sum0 = t_ ? s_[e] : sum0; mx0 = t_ ? m_[e] : mx0; }
        #pragma unroll
        for (int e = 1; e <= 4; ++e) { bool t_ = (o1 >= (unsigned)e); sum1 = t_ ? s_[e] : sum1; mx1 = t_ ? m_[e] : mx1; }
        #pragma unroll
        for (int e = 1; e <= 5; ++e) { bool t_ = (o2 >= (unsigned)e); sum2 = t_ ? s_[e] : sum2; mx2 = t_ ? m_[e] : mx2; }
        #pragma unroll
        for (int e = 1; e <= 6; ++e) { bool t_ = (o3 >= (unsigned)e); sum3 = t_ ? s_[e] : sum3; mx3 = t_ ? m_[e] : mx3; }
        const float4 R = resS4[(iq0 - j_lo_al) >> 2];
        const float a2l = a2S[p2_0 - p2_i0], a2h = a2S[p2_3 - p2_i0];
        const float m2l = m2S[p2_0 - p2_i0], m2h = m2S[p2_3 - p2_i0];
        const float a2_1 = (p2_1 != p2_0) ? a2h : a2l;
        const float a2_2 = (p2_2 != p2_0) ? a2h : a2l;
        const float m2_1 = (p2_1 != p2_0) ? m2h : m2l;
        const float m2_2 = (p2_2 != p2_0) ? m2h : m2l;
        float4 v0, v1, v2, v3;
        v0.x = sum0 * inv9 + R.x; v0.y = sum1 * inv9 + R.y; v0.z = sum2 * inv9 + R.z; v0.w = sum3 * inv9 + R.w;
        v1.x = a2l + R.x;         v1.y = a2_1 + R.y;        v1.z = a2_2 + R.z;        v1.w = a2h + R.w;
        v2.x = mx0 + R.x;         v2.y = mx1 + R.y;         v2.z = mx2 + R.z;         v2.w = mx3 + R.w;
        v3.x = m2l + R.x;         v3.y = m2_1 + R.y;        v3.z = m2_2 + R.z;        v3.w = m2h + R.w;
        o0p[gq] = v0; o1p[gq] = v1; o2p[gq] = v2; o3p[gq] = v3;
    };

    auto dispatch = [&](unsigned D, int gA, int gB) {
        switch ((4u - (D & 3u)) & 3u) {
            case 0: fast_regime<0>(gA, gB, tid, D, j_lo_al, p2_i0, resS4, a2S, m2S, o0p, o1p, o2p, o3p); break;
            case 1: fast_regime<1>(gA, gB, tid, D, j_lo_al, p2_i0, resS4, a2S, m2S, o0p, o1p, o2p, o3p); break;
            case 2: fast_regime<2>(gA, gB, tid, D, j_lo_al, p2_i0, resS4, a2S, m2S, o0p, o1p, o2p, o3p); break;
            default: fast_regime<3>(gA, gB, tid, D, j_lo_al, p2_i0, resS4, a2S, m2S, o0p, o1p, o2p, o3p); break;
        }
    };

    // regime 0: [i0, (nb>=1 ? bA-1 : i_last)]
    {
        const unsigned re = (nb >= 1) ? (bA - 1u) : i_last;
        dispatch(d_i0, (int)((i0 + 3u) >> 2), ((int)re - 3) >> 2);
    }
    if (nb >= 1) {  // regime 1: [bA, (nb>=2 ? bB-1 : i_last)]
        const unsigned re = (nb >= 2) ? (bB - 1u) : i_last;
        dispatch(d_i0 + 1u, (int)((bA + 3u) >> 2), ((int)re - 3) >> 2);
    }
    if (nb >= 2) {  // regime 2: [bB, i_last]
        dispatch(d_i0 + 2u, (int)((bB + 3u) >> 2), ((int)i_last - 3) >> 2);
    }
    // boundary-straddling quads (at most 2 per segment)
    if (nb >= 1 && (bA & 3u) && tid == 0) general_quad((int)(bA >> 2));
    if (nb >= 2 && (bB & 3u) && tid == 1) general_quad((int)(bB >> 2));
}

extern "C" void kernel_launch(void* const* d_in, const int* in_sizes, int n_in,
                              void* d_out, int out_size, void* d_ws, size_t ws_size,
                              hipStream_t stream) {
    const float* x = (const float*)d_in[0];
    float* out = (float*)d_out;
    // 256 batches x 4 channels x 8 segments = 8192 blocks
    derive_kernel<<<dim3(256 * 4 * NSEG), dim3(256), 0, stream>>>(x, out);
}

// Round 9
// 54.037 us; speedup vs baseline: 1.2910x; 1.2910x over previous
//
#include <hip/hip_runtime.h>

#define MAX_LEN 16384
#define RES_LEN 16372   // (16384 - 4) - 9 + 1
#define NSEG    4       // segments per row
#define SEG     4096    // outputs per segment (last = 4084)

__global__ __launch_bounds__(256, 6)
void derive_kernel(const float* __restrict__ x, float* __restrict__ out) {
    const int bid = blockIdx.x;
    const int b = bid >> 4;
    const int c = (bid >> 2) & 3;
    const int s = bid & 3;

    const float*  __restrict__ xr  = x + (size_t)b * MAX_LEN;
    const float4* __restrict__ xr4 = (const float4*)xr;

    // ---- segment geometry (unsigned-32 safe) ----
    const unsigned i0     = (unsigned)s * SEG;
    const unsigned i_last = (s == NSEG - 1) ? (RES_LEN - 1) : (i0 + SEG - 1);
    const int      nq     = (s == NSEG - 1) ? 1021 : 1024;   // output quads
    const unsigned p1_i0  = (i0 * 16364u) / 16372u;
    const unsigned p2_i0  = (i0 * 1819u)  / 16372u;
    const unsigned p1_lst = (i_last * 16364u) / 16372u;
    const unsigned p2_lst = (i_last * 1819u)  / 16372u;
    const unsigned j_lo   = min(p1_i0, 9u * p2_i0);
    const unsigned j_lo_al = j_lo & ~3u;
    const unsigned j_hi   = max(p1_lst, 9u * p2_lst) + 8u;
    const int      nqw    = (int)((j_hi - j_lo_al + 1u + 3u) >> 2);
    const int      xqb    = (int)(j_lo_al >> 2);
    const int      np2    = (int)(p2_lst - p2_i0 + 1u);

    __shared__ float4 resS4[1036];
    __shared__ float  a2S[456];
    __shared__ float  m2S[456];
    float* resS = (float*)resS4;

    const float inv9 = 1.0f / 9.0f;
    const int tid = threadIdx.x;

    // ---- Phase 1: res window into LDS (telescoped 9-avg of shifted diffs) ----
    for (int g = tid; g < nqw; g += 256) {
        const int gi = xqb + g;
        float4 A  = xr4[gi];
        float4 B4 = xr4[min(gi + 1, 4095)];
        float4 C4 = xr4[min(gi + 2, 4095)];
        float4 D4 = xr4[min(gi + 3, 4095)];
        float xv[16];
        xv[0]=A.x;  xv[1]=A.y;  xv[2]=A.z;  xv[3]=A.w;
        xv[4]=B4.x; xv[5]=B4.y; xv[6]=B4.z; xv[7]=B4.w;
        xv[8]=C4.x; xv[9]=C4.y; xv[10]=C4.z; xv[11]=C4.w;
        xv[12]=D4.x; xv[13]=D4.y; xv[14]=D4.z; xv[15]=D4.w;
        float rr[4];
        if (c == 0) {
            #pragma unroll
            for (int j = 0; j < 4; ++j) rr[j] = (xv[j+12] - xv[j+3]) * inv9;
        } else if (c == 1) {
            #pragma unroll
            for (int j = 0; j < 4; ++j) rr[j] = ((xv[j+12] + xv[j+11]) - (xv[j+3] + xv[j+2])) * inv9;
        } else if (c == 2) {
            #pragma unroll
            for (int j = 0; j < 4; ++j) rr[j] = ((xv[j+9] + xv[j+10] + xv[j+11] + xv[j+12])
                                               - (xv[j] + xv[j+1] + xv[j+2] + xv[j+3])) * inv9;
        } else {
            #pragma unroll
            for (int j = 0; j < 4; ++j) rr[j] = ((xv[j+12] - xv[j+11]) - (xv[j+3] - xv[j+2])) * inv9;
        }
        float4 rv; rv.x = rr[0]; rv.y = rr[1]; rv.z = rr[2]; rv.w = rr[3];
        resS4[g] = rv;
    }
    __syncthreads();

    // ---- Phase 2: local stride-9 pools ----
    for (int t = tid; t < np2; t += 256) {
        const int j0 = (int)(9u * (p2_i0 + (unsigned)t) - j_lo_al);
        float sm = resS[j0], mm = resS[j0];
        #pragma unroll
        for (int k = 1; k < 9; ++k) { float v = resS[j0 + k]; sm += v; mm = fmaxf(mm, v); }
        a2S[t] = sm * inv9; m2S[t] = mm;
    }
    __syncthreads();

    // ---- Phase 3: four sequential contiguous-stream sweeps ----
    float* outBase = out + ((size_t)b * 16 + c) * RES_LEN;
    float4* o0p = (float4*)(outBase);
    float4* o1p = (float4*)(outBase + 4 * RES_LEN);
    float4* o2p = (float4*)(outBase + 8 * RES_LEN);
    float4* o3p = (float4*)(outBase + 12 * RES_LEN);
    const int gq0 = (int)(i0 >> 2);

    // -- 3a: branch 0 (sliding avgpool(9,1) + res), one contiguous stream --
    for (int t = tid; t < nq; t += 256) {
        const int gq = gq0 + t;
        const unsigned iq0 = 4u * (unsigned)gq;
        const unsigned p1_0 = (iq0 * 16364u) / 16372u;
        const unsigned p1_1 = ((iq0 + 1u) * 16364u) / 16372u;
        const unsigned p1_2 = ((iq0 + 2u) * 16364u) / 16372u;
        const unsigned p1_3 = ((iq0 + 3u) * 16364u) / 16372u;
        const unsigned li0 = p1_0 - j_lo_al;
        const unsigned q   = li0 >> 2;
        const unsigned o0  = li0 & 3u;
        const unsigned o1  = (p1_1 - j_lo_al) - 4u * q;
        const unsigned o2  = (p1_2 - j_lo_al) - 4u * q;
        const unsigned o3  = (p1_3 - j_lo_al) - 4u * q;

        float4 W0 = resS4[q], W1 = resS4[q + 1], W2 = resS4[q + 2], W3 = resS4[q + 3];
        float w[16];
        w[0]=W0.x;  w[1]=W0.y;  w[2]=W0.z;  w[3]=W0.w;
        w[4]=W1.x;  w[5]=W1.y;  w[6]=W1.z;  w[7]=W1.w;
        w[8]=W2.x;  w[9]=W2.y;  w[10]=W2.z; w[11]=W2.w;
        w[12]=W3.x; w[13]=W3.y; w[14]=W3.z; w[15]=W3.w;

        float s_[7];
        s_[0] = ((((((((w[0] + w[1]) + w[2]) + w[3]) + w[4]) + w[5]) + w[6]) + w[7]) + w[8]);
        #pragma unroll
        for (int e = 1; e < 7; ++e) s_[e] = s_[e - 1] - w[e - 1] + w[e + 8];

        float sum0 = s_[0], sum1 = s_[0], sum2 = s_[0], sum3 = s_[0];
        #pragma unroll
        for (int e = 1; e <= 3; ++e) { if (o0 >= (unsigned)e) sum0 = s_[e]; }
        #pragma unroll
        for (int e = 1; e <= 4; ++e) { if (o1 >= (unsigned)e) sum1 = s_[e]; }
        #pragma unroll
        for (int e = 1; e <= 5; ++e) { if (o2 >= (unsigned)e) sum2 = s_[e]; }
        #pragma unroll
        for (int e = 1; e <= 6; ++e) { if (o3 >= (unsigned)e) sum3 = s_[e]; }

        const float4 R = resS4[(iq0 - j_lo_al) >> 2];
        float4 v0;
        v0.x = sum0 * inv9 + R.x; v0.y = sum1 * inv9 + R.y;
        v0.z = sum2 * inv9 + R.z; v0.w = sum3 * inv9 + R.w;
        o0p[gq] = v0;
    }

    // -- 3b: branch 2 (sliding maxpool(9,1) + res), one contiguous stream --
    for (int t = tid; t < nq; t += 256) {
        const int gq = gq0 + t;
        const unsigned iq0 = 4u * (unsigned)gq;
        const unsigned p1_0 = (iq0 * 16364u) / 16372u;
        const unsigned p1_1 = ((iq0 + 1u) * 16364u) / 16372u;
        const unsigned p1_2 = ((iq0 + 2u) * 16364u) / 16372u;
        const unsigned p1_3 = ((iq0 + 3u) * 16364u) / 16372u;
        const unsigned li0 = p1_0 - j_lo_al;
        const unsigned q   = li0 >> 2;
        const unsigned o0  = li0 & 3u;
        const unsigned o1  = (p1_1 - j_lo_al) - 4u * q;
        const unsigned o2  = (p1_2 - j_lo_al) - 4u * q;
        const unsigned o3  = (p1_3 - j_lo_al) - 4u * q;

        float4 W0 = resS4[q], W1 = resS4[q + 1], W2 = resS4[q + 2], W3 = resS4[q + 3];
        float w[16];
        w[0]=W0.x;  w[1]=W0.y;  w[2]=W0.z;  w[3]=W0.w;
        w[4]=W1.x;  w[5]=W1.y;  w[6]=W1.z;  w[7]=W1.w;
        w[8]=W2.x;  w[9]=W2.y;  w[10]=W2.z; w[11]=W2.w;
        w[12]=W3.x; w[13]=W3.y; w[14]=W3.z; w[15]=W3.w;

        float suf[7];
        suf[6] = fmaxf(fmaxf(w[6], w[7]), w[8]);
        #pragma unroll
        for (int u = 5; u >= 0; --u) suf[u] = fmaxf(w[u], suf[u + 1]);
        float pre[15];
        pre[8] = w[8];
        #pragma unroll
        for (int u = 9; u < 15; ++u) pre[u] = fmaxf(pre[u - 1], w[u]);
        float m_[7];
        #pragma unroll
        for (int o = 0; o < 7; ++o) m_[o] = fmaxf(suf[o], pre[o + 8]);

        float mx0 = m_[0], mx1 = m_[0], mx2 = m_[0], mx3 = m_[0];
        #pragma unroll
        for (int e = 1; e <= 3; ++e) { if (o0 >= (unsigned)e) mx0 = m_[e]; }
        #pragma unroll
        for (int e = 1; e <= 4; ++e) { if (o1 >= (unsigned)e) mx1 = m_[e]; }
        #pragma unroll
        for (int e = 1; e <= 5; ++e) { if (o2 >= (unsigned)e) mx2 = m_[e]; }
        #pragma unroll
        for (int e = 1; e <= 6; ++e) { if (o3 >= (unsigned)e) mx3 = m_[e]; }

        const float4 R = resS4[(iq0 - j_lo_al) >> 2];
        float4 v2;
        v2.x = mx0 + R.x; v2.y = mx1 + R.y; v2.z = mx2 + R.z; v2.w = mx3 + R.w;
        o2p[gq] = v2;
    }

    // -- 3c: branch 1 (upsampled avgpool(9,9) + res), one contiguous stream --
    for (int t = tid; t < nq; t += 256) {
        const int gq = gq0 + t;
        const unsigned iq0 = 4u * (unsigned)gq;
        const unsigned p2_0 = (iq0 * 1819u) / 16372u;
        const unsigned p2_1 = ((iq0 + 1u) * 1819u) / 16372u;
        const unsigned p2_2 = ((iq0 + 2u) * 1819u) / 16372u;
        const unsigned p2_3 = ((iq0 + 3u) * 1819u) / 16372u;
        const float a2l = a2S[p2_0 - p2_i0], a2h = a2S[p2_3 - p2_i0];
        const float a2_1 = (p2_1 != p2_0) ? a2h : a2l;
        const float a2_2 = (p2_2 != p2_0) ? a2h : a2l;
        const float4 R = resS4[(iq0 - j_lo_al) >> 2];
        float4 v1;
        v1.x = a2l + R.x; v1.y = a2_1 + R.y; v1.z = a2_2 + R.z; v1.w = a2h + R.w;
        o1p[gq] = v1;
    }

    // -- 3d: branch 3 (upsampled maxpool(9,9) + res), one contiguous stream --
    for (int t = tid; t < nq; t += 256) {
        const int gq = gq0 + t;
        const unsigned iq0 = 4u * (unsigned)gq;
        const unsigned p2_0 = (iq0 * 1819u) / 16372u;
        const unsigned p2_1 = ((iq0 + 1u) * 1819u) / 16372u;
        const unsigned p2_2 = ((iq0 + 2u) * 1819u) / 16372u;
        const unsigned p2_3 = ((iq0 + 3u) * 1819u) / 16372u;
        const float m2l = m2S[p2_0 - p2_i0], m2h = m2S[p2_3 - p2_i0];
        const float m2_1 = (p2_1 != p2_0) ? m2h : m2l;
        const float m2_2 = (p2_2 != p2_0) ? m2h : m2l;
        const float4 R = resS4[(iq0 - j_lo_al) >> 2];
        float4 v3;
        v3.x = m2l + R.x; v3.y = m2_1 + R.y; v3.z = m2_2 + R.z; v3.w = m2h + R.w;
        o3p[gq] = v3;
    }
}

extern "C" void kernel_launch(void* const* d_in, const int* in_sizes, int n_in,
                              void* d_out, int out_size, void* d_ws, size_t ws_size,
                              hipStream_t stream) {
    const float* x = (const float*)d_in[0];
    float* out = (float*)d_out;
    // 256 batches x 4 channels x 4 segments = 4096 blocks
    derive_kernel<<<dim3(256 * 4 * NSEG), dim3(256), 0, stream>>>(x, out);
}